// Round 16
// baseline (915.884 us; speedup 1.0000x reference)
//
#include <hip/hip_runtime.h>
#include <cmath>

#define NB 16
#define TSEQ 1024
#define DIN 16
#define DM 512
#define DFFN 2048
#define NLAYERS 4
#define DOUTN 3
#define ROWS (NB*TSEQ)   /* 16384 */

typedef unsigned short u16;
typedef unsigned int   u32;
typedef short bf16x8 __attribute__((ext_vector_type(8)));
typedef u16   u16x4  __attribute__((ext_vector_type(4)));
typedef float f32x4  __attribute__((ext_vector_type(4)));

__device__ __forceinline__ float b2f(u16 v) { return __uint_as_float((unsigned)v << 16); }
__device__ __forceinline__ u16 f2b(float f) {
    unsigned u = __float_as_uint(f);
    return (u16)((u + 0x7FFFu + ((u >> 16) & 1u)) >> 16);
}

#define GLL(gp, lp) __builtin_amdgcn_global_load_lds( \
    (const __attribute__((address_space(1))) unsigned int*)(gp), \
    (__attribute__((address_space(3))) unsigned int*)(lp), 16, 0, 0)

#define WAITVM2() asm volatile("s_waitcnt vmcnt(2)" ::: "memory")
#define WAITVM0() asm volatile("s_waitcnt vmcnt(0)" ::: "memory")
#define BARR() do { asm volatile("" ::: "memory"); __builtin_amdgcn_s_barrier(); \
                    asm volatile("" ::: "memory"); } while (0)

// ------------------------------------------------- weight transpose + cast
template<int PERM>
__global__ __launch_bounds__(256) void transpose_cast(
    const float* __restrict__ in, u16* __restrict__ out,
    int K, int N, size_t in_lstride, size_t out_lstride)
{
    in  += (size_t)blockIdx.z * in_lstride;
    out += (size_t)blockIdx.z * out_lstride;
    __shared__ float t[32][33];
    int bk = blockIdx.x * 32, bn = blockIdx.y * 32;
    int x = threadIdx.x & 31, y = threadIdx.x >> 5;
    #pragma unroll
    for (int i = 0; i < 32; i += 8)
        t[y + i][x] = in[(size_t)(bk + y + i) * N + bn + x];
    __syncthreads();
    #pragma unroll
    for (int i = 0; i < 32; i += 8) {
        int row = bn + y + i;
        if (PERM) row = ((row & 63) << 3) | ((row >> 6) & 7);
        out[(size_t)row * K + bk + x] = f2b(t[x][y + i]);
    }
}

// ------------------------------------------------- encode (bf16 out)
__global__ __launch_bounds__(128) void encode_kernel(
    const float* __restrict__ x, const int* __restrict__ pad,
    const float* __restrict__ W, const float* __restrict__ b,
    u16* __restrict__ h)
{
    int row = blockIdx.x;
    int t   = row & (TSEQ - 1);
    int c   = threadIdx.x * 4;
    float acc[4];
    #pragma unroll
    for (int j = 0; j < 4; ++j) acc[j] = b[c + j];
    const float* xr = x + (size_t)row * DIN;
    #pragma unroll
    for (int k = 0; k < DIN; ++k) {
        float xv = xr[k];
        const float* wr = W + (size_t)k * DM + c;
        #pragma unroll
        for (int j = 0; j < 4; ++j) acc[j] += xv * wr[j];
    }
    const float s = 22.62741699796952f;
    bool has_pe = (pad[row] != 0);
    u16x4 o;
    #pragma unroll
    for (int j = 0; j < 4; ++j) {
        acc[j] *= s;
        if (has_pe) {
            int d = c + j;
            float base = (float)t * powf(10000.0f, -(float)d * (1.0f/512.0f));
            acc[j] += ((d & 1) == 0) ? sinf(base) : cosf(base);
        }
        o[j] = f2b(acc[j]);
    }
    *(u16x4*)&h[(size_t)row * DM + c] = o;
}

// ------------------------------------------------- 128x128 MFMA GEMM (r11 2-phase, proven)
// 512 thr, BK=64, G4 swizzle, A+B double-buffered (64KB); 8 waves (2M x 4N).
template<int BIAS, int RELU>
__global__ __launch_bounds__(512, 4) void gemm128(
    const u16* __restrict__ A, const u16* __restrict__ Bt,
    const float* __restrict__ bias, u16* __restrict__ C,
    int M, int N, int K)
{
    __shared__ u16 S[4][8192];
    const int tid  = threadIdx.x;
    const int lane = tid & 63;
    const int wid  = tid >> 6;
    const int wr   = wid >> 2;
    const int wc   = wid & 3;

    const int NY  = N >> 7;
    const int nwg = gridDim.x;
    const int cpx = nwg >> 3;
    const int bid = blockIdx.x;
    const int swz = (bid & 7) * cpx + (bid >> 3);
    const int bm  = (swz / NY) * 128;
    const int bn  = (swz % NY) * 128;

    const int srow8 = lane >> 3;
    const int sslot = lane & 7;
    const int scol  = ((sslot ^ srow8) * 8);
    const u16* Ag = A  + (size_t)(bm + wid * 16 + srow8) * K + scol;
    const u16* Bg = Bt + (size_t)(bn + wid * 16 + srow8) * K + scol;

    f32x4 acc[4][2];
    #pragma unroll
    for (int m = 0; m < 4; ++m)
        #pragma unroll
        for (int n = 0; n < 2; ++n)
            acc[m][n] = (f32x4){0.f, 0.f, 0.f, 0.f};

    const int fr  = lane & 15;
    const int grp = lane >> 4;

    auto STAGE = [&](int k0, int d) {
        u16* Al = S[d * 2 + 0] + wid * 1024;
        u16* Bl = S[d * 2 + 1] + wid * 1024;
        #pragma unroll
        for (int i = 0; i < 2; ++i) {
            GLL(Ag + (size_t)(i * 8) * K + k0, Al + i * 512);
            GLL(Bg + (size_t)(i * 8) * K + k0, Bl + i * 512);
        }
    };

    STAGE(0, 0);
    __syncthreads();

    int cur = 0;
    for (int k0 = 0; k0 < K; k0 += 64) {
        if (k0 + 64 < K) STAGE(k0 + 64, cur ^ 1);
        const u16* As = S[cur * 2 + 0];
        const u16* Bs = S[cur * 2 + 1];
        bf16x8 a[4][2];
        #pragma unroll
        for (int m = 0; m < 4; ++m) {
            int row = wr * 64 + m * 16 + fr;
            #pragma unroll
            for (int ks = 0; ks < 2; ++ks) {
                int slot = (ks * 4 + grp) ^ (row & 7);
                a[m][ks] = *(const bf16x8*)(As + row * 64 + slot * 8);
            }
        }
        #pragma unroll
        for (int n = 0; n < 2; ++n) {
            bf16x8 b[2];
            int row = wc * 32 + n * 16 + fr;
            #pragma unroll
            for (int ks = 0; ks < 2; ++ks) {
                int slot = (ks * 4 + grp) ^ (row & 7);
                b[ks] = *(const bf16x8*)(Bs + row * 64 + slot * 8);
            }
            #pragma unroll
            for (int m = 0; m < 4; ++m) {
                acc[m][n] = __builtin_amdgcn_mfma_f32_16x16x32_bf16(a[m][0], b[0], acc[m][n], 0, 0, 0);
                acc[m][n] = __builtin_amdgcn_mfma_f32_16x16x32_bf16(a[m][1], b[1], acc[m][n], 0, 0, 0);
            }
        }
        __syncthreads();
        cur ^= 1;
    }

    float bb[2] = {0.f, 0.f};
    if (BIAS) {
        #pragma unroll
        for (int n = 0; n < 2; ++n) bb[n] = bias[bn + wc * 32 + n * 16 + fr];
    }
    #pragma unroll
    for (int m = 0; m < 4; ++m) {
        #pragma unroll
        for (int n = 0; n < 2; ++n) {
            int col = bn + wc * 32 + n * 16 + fr;
            #pragma unroll
            for (int j = 0; j < 4; ++j) {
                int row = bm + wr * 64 + m * 16 + grp * 4 + j;
                float v = acc[m][n][j];
                if (BIAS) v += bb[n];
                if (RELU) v = fmaxf(v, 0.f);
                C[(size_t)row * N + col] = f2b(v);
            }
        }
    }
}

// ------------------------------------------------- 128x128 MFMA GEMM, BK=32,
// 3-deep pipeline, UNROLLED x3 with STATIC buffers + plain LDS reads.
// Tests: compiler alias-precision -> counted vmcnt sticks (no per-iter drain).
// Requires K/32 % 3 == 1 (true for K=512 and K=2048).
template<int BIAS, int RELU>
__global__ __launch_bounds__(512, 6) void gemm3d(
    const u16* __restrict__ A, const u16* __restrict__ Bt,
    const float* __restrict__ bias, u16* __restrict__ C,
    int M, int N, int K)
{
    __shared__ u16 S0a[4096], S0b[4096];
    __shared__ u16 S1a[4096], S1b[4096];
    __shared__ u16 S2a[4096], S2b[4096];
    const int tid  = threadIdx.x;
    const int lane = tid & 63;
    const int wid  = tid >> 6;
    const int wr   = wid >> 2;          // 0..1 (M half)
    const int wc   = wid & 3;           // 0..3 (N quarter)

    const int NY  = N >> 7;
    const int nwg = gridDim.x;
    const int cpx = nwg >> 3;
    const int bid = blockIdx.x;
    const int swz = (bid & 7) * cpx + (bid >> 3);
    const int bm  = (swz / NY) * 128;
    const int bn  = (swz % NY) * 128;

    const int srow   = tid >> 2;
    const int schunk = (tid & 3) ^ ((srow >> 1) & 3);
    const u16* Ag = A  + (size_t)(bm + srow) * K + schunk * 8;
    const u16* Bg = Bt + (size_t)(bn + srow) * K + schunk * 8;

    f32x4 acc[4][2];
    #pragma unroll
    for (int m = 0; m < 4; ++m)
        #pragma unroll
        for (int n = 0; n < 2; ++n)
            acc[m][n] = (f32x4){0.f, 0.f, 0.f, 0.f};

    const int fr  = lane & 15;
    const int grp = lane >> 4;

    const int nt = K >> 5;   // tiles; nt % 3 == 1 for K in {512, 2048}

#define STAGE3(kt, DA, DB) do { \
        GLL(Ag + (size_t)(kt) * 32, DA + tid * 8); \
        GLL(Bg + (size_t)(kt) * 32, DB + tid * 8); } while (0)

#define STEP3(t, RA, RB, SA_, SB_, doStage, last) do { \
        if (last) { WAITVM0(); } else { WAITVM2(); } \
        BARR(); \
        if (doStage) STAGE3((t) + 2, SA_, SB_); \
        bf16x8 a_[4], b_[2]; \
        _Pragma("unroll") \
        for (int m = 0; m < 4; ++m) { \
            int row = wr * 64 + m * 16 + fr; \
            int slot = grp ^ ((row >> 1) & 3); \
            a_[m] = *(const bf16x8*)(RA + row * 32 + slot * 8); \
        } \
        _Pragma("unroll") \
        for (int n = 0; n < 2; ++n) { \
            int row = wc * 32 + n * 16 + fr; \
            int slot = grp ^ ((row >> 1) & 3); \
            b_[n] = *(const bf16x8*)(RB + row * 32 + slot * 8); \
        } \
        _Pragma("unroll") \
        for (int n = 0; n < 2; ++n) \
            _Pragma("unroll") \
            for (int m = 0; m < 4; ++m) \
                acc[m][n] = __builtin_amdgcn_mfma_f32_16x16x32_bf16(a_[m], b_[n], acc[m][n], 0, 0, 0); \
    } while (0)

    STAGE3(0, S0a, S0b);
    STAGE3(1, S1a, S1b);

    for (int it = 0; it + 3 < nt; it += 3) {
        STEP3(it + 0, S0a, S0b, S2a, S2b, (it + 2 < nt), false);
        STEP3(it + 1, S1a, S1b, S0a, S0b, (it + 3 < nt), false);
        STEP3(it + 2, S2a, S2b, S1a, S1b, (it + 4 < nt), false);
    }
    // tail: nt % 3 == 1 -> last tile index nt-1, buffer 0
    STEP3(nt - 1, S0a, S0b, S1a, S1b, false, true);

#undef STEP3
#undef STAGE3

    float bb[2] = {0.f, 0.f};
    if (BIAS) {
        #pragma unroll
        for (int n = 0; n < 2; ++n) bb[n] = bias[bn + wc * 32 + n * 16 + fr];
    }
    #pragma unroll
    for (int m = 0; m < 4; ++m) {
        #pragma unroll
        for (int n = 0; n < 2; ++n) {
            int col = bn + wc * 32 + n * 16 + fr;
            #pragma unroll
            for (int j = 0; j < 4; ++j) {
                int row = bm + wr * 64 + m * 16 + grp * 4 + j;
                float v = acc[m][n][j];
                if (BIAS) v += bb[n];
                if (RELU) v = fmaxf(v, 0.f);
                C[(size_t)row * N + col] = f2b(v);
            }
        }
    }
}

// ------------------------------------------------- attention v3 (swapped QK^T)
__global__ __launch_bounds__(256) void attn_mfma(
    const u16* __restrict__ QKV, const int* __restrict__ pad,
    u16* __restrict__ O)
{
    constexpr int WLDS = 2560;
    __shared__ u16 sh[4 * WLDS];
    const int wid  = threadIdx.x >> 6;
    const int lane = threadIdx.x & 63;
    const int site = blockIdx.x * 4 + wid;
    u16* P2 = sh + wid * WLDS;
    u16* Ol = P2 + 2048;

    const u16* base = QKV + (size_t)site * 1536;
    const int fr  = lane & 15;
    const int grp = lane >> 4;
    const bf16x8 zb = {0,0,0,0,0,0,0,0};
    const f32x4  zf = {0.f,0.f,0.f,0.f};

    if (pad[site] == 0) {
        bf16x8 vv = *(const bf16x8*)(base + 1024 + lane * 8);
        float s = 0.f;
        #pragma unroll
        for (int j = 0; j < 8; ++j) s += b2f((u16)vv[j]);
        s += __shfl_xor(s, 1); s += __shfl_xor(s, 2); s += __shfl_xor(s, 4);
        s *= (1.0f / 64.0f);
        bf16x8 ov;
        #pragma unroll
        for (int h2 = 0; h2 < 8; ++h2) ov[h2] = (short)f2b(__shfl(s, h2 * 8));
        *(bf16x8*)(O + (size_t)site * DM + lane * 8) = ov;
        return;
    }

    bf16x8 kt[4];
    #pragma unroll
    for (int n = 0; n < 4; ++n)
        kt[n] = (grp == 0) ? *(const bf16x8*)(base + 512 + (n * 16 + fr) * 8) : zb;
    bf16x8 bv[2];
    #pragma unroll
    for (int ks = 0; ks < 2; ++ks)
        bv[ks] = (fr < 8) ? *(const bf16x8*)(base + 1024 + fr * 64 + ks * 32 + grp * 8) : zb;

    const int swz = (fr & 3) ^ (fr >> 2);
    u16x4 pk23[4][2];

    #pragma unroll
    for (int m = 0; m < 4; ++m) {
        bf16x8 aq = (grp == 0) ? *(const bf16x8*)(base + (m * 16 + fr) * 8) : zb;
        f32x4 ev[4];
        #pragma unroll
        for (int n = 0; n < 4; ++n)
            ev[n] = __builtin_amdgcn_mfma_f32_16x16x32_bf16(kt[n], aq, zf, 0, 0, 0);
        f32x4 t0, t1;
        #pragma unroll
        for (int j = 0; j < 4; ++j) { t0[j] = fmaxf(ev[0][j], ev[1][j]); t1[j] = fmaxf(ev[2][j], ev[3][j]); }
        float mx = -1e30f;
        #pragma unroll
        for (int j = 0; j < 4; ++j) mx = fmaxf(mx, fmaxf(t0[j], t1[j]));
        mx = fmaxf(mx, __shfl_xor(mx, 16));
        mx = fmaxf(mx, __shfl_xor(mx, 32));
        float p[4][4];
        float s = 0.f;
        #pragma unroll
        for (int n = 0; n < 4; ++n)
            #pragma unroll
            for (int j = 0; j < 4; ++j) {
                p[n][j] = __expf((ev[n][j] - mx) * 0.03125f);
                s += p[n][j];
            }
        s += __shfl_xor(s, 16);
        s += __shfl_xor(s, 32);
        float inv = 1.0f / s;
        u16x4 pk[4];
        #pragma unroll
        for (int n = 0; n < 4; ++n)
            #pragma unroll
            for (int j = 0; j < 4; ++j) pk[n][j] = f2b(p[n][j] * inv);
        int row = m * 16 + fr;
        #pragma unroll
        for (int n = 0; n < 2; ++n) {
            int chunk = (n * 2 + (grp >> 1)) ^ swz;
            *(u16x4*)(P2 + row * 32 + chunk * 8 + (grp & 1) * 4) = pk[n];
        }
        pk23[m][0] = pk[2];
        pk23[m][1] = pk[3];
    }

    f32x4 pv[4];
    #pragma unroll
    for (int m = 0; m < 4; ++m) {
        int row = m * 16 + fr;
        bf16x8 ap = *(const bf16x8*)(P2 + row * 32 + ((grp ^ swz) * 8));
        pv[m] = __builtin_amdgcn_mfma_f32_16x16x32_bf16(ap, bv[0], zf, 0, 0, 0);
    }
    asm volatile("s_waitcnt lgkmcnt(0)" ::: "memory");
    __builtin_amdgcn_sched_barrier(0);

    #pragma unroll
    for (int m = 0; m < 4; ++m) {
        int row = m * 16 + fr;
        #pragma unroll
        for (int n = 0; n < 2; ++n) {
            int chunk = (n * 2 + (grp >> 1)) ^ swz;
            *(u16x4*)(P2 + row * 32 + chunk * 8 + (grp & 1) * 4) = pk23[m][n];
        }
    }
    #pragma unroll
    for (int m = 0; m < 4; ++m) {
        int row = m * 16 + fr;
        bf16x8 ap = *(const bf16x8*)(P2 + row * 32 + ((grp ^ swz) * 8));
        pv[m] = __builtin_amdgcn_mfma_f32_16x16x32_bf16(ap, bv[1], pv[m], 0, 0, 0);
    }

    #pragma unroll
    for (int m = 0; m < 4; ++m)
        #pragma unroll
        for (int j = 0; j < 4; ++j) {
            int row = m * 16 + grp * 4 + j;
            if (fr < 8) Ol[row * 8 + fr] = f2b(pv[m][j]);
        }
    __syncthreads();
    bf16x8 o = *(const bf16x8*)(Ol + lane * 8);
    *(bf16x8*)(O + (size_t)site * DM + lane * 8) = o;
}

// ------------------------------------------------- residual add + layernorm (bf16)
__global__ __launch_bounds__(256) void add_ln_kernel(
    const u16* __restrict__ A, u16* __restrict__ H,
    const float* __restrict__ g, const float* __restrict__ b)
{
    int row  = blockIdx.x * 4 + (threadIdx.x >> 6);
    int lane = threadIdx.x & 63;
    const u16* a = A + (size_t)row * DM + lane * 8;
    u16* h = H + (size_t)row * DM + lane * 8;
    bf16x8 av = *(const bf16x8*)a;
    bf16x8 hv = *(const bf16x8*)h;
    float v[8];
    float s = 0.f;
    #pragma unroll
    for (int j = 0; j < 8; ++j) { v[j] = b2f((u16)av[j]) + b2f((u16)hv[j]); s += v[j]; }
    #pragma unroll
    for (int off = 32; off > 0; off >>= 1) s += __shfl_xor(s, off, 64);
    float mean = s * (1.0f / 512.0f);
    float var = 0.f;
    #pragma unroll
    for (int j = 0; j < 8; ++j) { float d = v[j] - mean; var += d * d; }
    #pragma unroll
    for (int off = 32; off > 0; off >>= 1) var += __shfl_xor(var, off, 64);
    float rstd = rsqrtf(var * (1.0f / 512.0f) + 1e-5f);
    bf16x8 ov;
    #pragma unroll
    for (int j = 0; j < 8; ++j) {
        int d = lane * 8 + j;
        ov[j] = (short)f2b((v[j] - mean) * rstd * g[d] + b[d]);
    }
    *(bf16x8*)h = ov;
}

// ------------------------------------------------- final projection
__global__ __launch_bounds__(256) void out_stage1(
    const u16* __restrict__ h, const float* __restrict__ W,
    float* __restrict__ partial)
{
    int b = blockIdx.x, s = blockIdx.y;
    int tid = threadIdx.x;
    const u16* hb = h + (size_t)b * (TSEQ * DM) + (size_t)s * 8192;
    const float* Wb = W + (size_t)s * 8192 * 3;
    float a0 = 0.f, a1 = 0.f, a2 = 0.f;
    #pragma unroll 4
    for (int it = 0; it < 32; ++it) {
        int i = it * 256 + tid;
        float hv = b2f(hb[i]);
        a0 += hv * Wb[i * 3 + 0];
        a1 += hv * Wb[i * 3 + 1];
        a2 += hv * Wb[i * 3 + 2];
    }
    __shared__ float red[3][256];
    red[0][tid] = a0; red[1][tid] = a1; red[2][tid] = a2;
    __syncthreads();
    for (int off = 128; off > 0; off >>= 1) {
        if (tid < off) {
            red[0][tid] += red[0][tid + off];
            red[1][tid] += red[1][tid + off];
            red[2][tid] += red[2][tid + off];
        }
        __syncthreads();
    }
    if (tid == 0) {
        partial[(b * 64 + s) * 3 + 0] = red[0][0];
        partial[(b * 64 + s) * 3 + 1] = red[1][0];
        partial[(b * 64 + s) * 3 + 2] = red[2][0];
    }
}

__global__ __launch_bounds__(64) void out_stage2(
    const float* __restrict__ partial, const float* __restrict__ ob,
    float* __restrict__ out)
{
    int t = threadIdx.x;
    if (t < NB * DOUTN) {
        int b = t / 3, o = t % 3;
        float s = ob[o];
        for (int k = 0; k < 64; ++k) s += partial[(b * 64 + k) * 3 + o];
        out[t] = s;
    }
}

// ------------------------------------------------- launch
extern "C" void kernel_launch(void* const* d_in, const int* in_sizes, int n_in,
                              void* d_out, int out_size, void* d_ws, size_t ws_size,
                              hipStream_t stream)
{
    const float* x    = (const float*)d_in[0];
    const int*   pad  = (const int*)  d_in[1];
    const float* encW = (const float*)d_in[2];
    const float* encB = (const float*)d_in[3];
    const float* Wq   = (const float*)d_in[4];
    const float* Wk   = (const float*)d_in[5];
    const float* Wv   = (const float*)d_in[6];
    const float* Wo   = (const float*)d_in[7];
    const float* fW1  = (const float*)d_in[8];
    const float* fb1  = (const float*)d_in[9];
    const float* fW2  = (const float*)d_in[10];
    const float* fb2  = (const float*)d_in[11];
    const float* l1g  = (const float*)d_in[12];
    const float* l1b  = (const float*)d_in[13];
    const float* l2g  = (const float*)d_in[14];
    const float* l2b  = (const float*)d_in[15];
    const float* outW = (const float*)d_in[16];
    const float* outB = (const float*)d_in[17];
    float* out = (float*)d_out;

    const size_t WL  = 3145728;
    const size_t BUF = (size_t)ROWS * DM;
    const size_t need = (4 * WL + 6 * BUF) * sizeof(u16);
    if (ws_size < need) return;
    u16* wt = (u16*)d_ws;
    u16* h  = wt + 4 * WL;
    u16* b0 = h  + BUF;
    u16* b3 = b0 + 3 * BUF;
    u16* b4 = b3 + BUF;

    transpose_cast<1><<<dim3(16,16,4), 256, 0, stream>>>(Wq,  wt + 0,       512,  512,  (size_t)512*512,  WL);
    transpose_cast<1><<<dim3(16,16,4), 256, 0, stream>>>(Wk,  wt + 262144,  512,  512,  (size_t)512*512,  WL);
    transpose_cast<0><<<dim3(16,16,4), 256, 0, stream>>>(Wv,  wt + 524288,  512,  512,  (size_t)512*512,  WL);
    transpose_cast<0><<<dim3(16,16,4), 256, 0, stream>>>(Wo,  wt + 786432,  512,  512,  (size_t)512*512,  WL);
    transpose_cast<0><<<dim3(16,64,4), 256, 0, stream>>>(fW1, wt + 1048576, 512,  2048, (size_t)512*2048, WL);
    transpose_cast<0><<<dim3(64,16,4), 256, 0, stream>>>(fW2, wt + 2097152, 2048, 512,  (size_t)2048*512, WL);

    encode_kernel<<<ROWS, 128, 0, stream>>>(x, pad, encW, encB, h);

    for (int l = 0; l < NLAYERS; ++l) {
        u16* wl = wt + (size_t)l * WL;
        // QKV / Wo: proven 2-phase BK=64
        gemm128<0,0><<<dim3((ROWS/128)*(1536/128)), 512, 0, stream>>>(h, wl, nullptr, b0, ROWS, 1536, DM);
        attn_mfma<<<ROWS/4, 256, 0, stream>>>(b0, pad, b3);
        gemm128<0,0><<<dim3((ROWS/128)*(DM/128)), 512, 0, stream>>>(b3, wl + 786432, nullptr, b4, ROWS, DM, DM);
        add_ln_kernel<<<ROWS/4, 256, 0, stream>>>(b4, h, l1g + l*DM, l1b + l*DM);
        // FF1 / FF2: 3-deep static-buffer pipeline (K = 512 / 2048)
        gemm3d<1,1><<<dim3((ROWS/128)*(DFFN/128)), 512, 0, stream>>>(h, wl + 1048576, fb1 + (size_t)l*DFFN, b0, ROWS, DFFN, DM);
        gemm3d<1,0><<<dim3((ROWS/128)*(DM/128)), 512, 0, stream>>>(b0, wl + 2097152, fb2 + (size_t)l*DM, b4, ROWS, DM, DFFN);
        add_ln_kernel<<<ROWS/4, 256, 0, stream>>>(b4, h, l2g + l*DM, l2b + l*DM);
    }

    out_stage1<<<dim3(NB, 64), 256, 0, stream>>>(h, outW, (float*)b0);
    out_stage2<<<1, 64, 0, stream>>>((float*)b0, outB, out);
}

// Round 17
// 738.805 us; speedup vs baseline: 1.2397x; 1.2397x over previous
//
#include <hip/hip_runtime.h>
#include <cmath>

#define NB 16
#define TSEQ 1024
#define DIN 16
#define DM 512
#define DFFN 2048
#define NLAYERS 4
#define DOUTN 3
#define ROWS (NB*TSEQ)   /* 16384 */

typedef unsigned short u16;
typedef unsigned int   u32;
typedef short bf16x8 __attribute__((ext_vector_type(8)));
typedef u16   u16x4  __attribute__((ext_vector_type(4)));
typedef float f32x4  __attribute__((ext_vector_type(4)));

__device__ __forceinline__ float b2f(u16 v) { return __uint_as_float((unsigned)v << 16); }
__device__ __forceinline__ u16 f2b(float f) {
    unsigned u = __float_as_uint(f);
    return (u16)((u + 0x7FFFu + ((u >> 16) & 1u)) >> 16);
}

#define GLL(gp, lp) __builtin_amdgcn_global_load_lds( \
    (const __attribute__((address_space(1))) unsigned int*)(gp), \
    (__attribute__((address_space(3))) unsigned int*)(lp), 16, 0, 0)

// ------------------------------------------------- weight transpose + cast
template<int PERM>
__global__ __launch_bounds__(256) void transpose_cast(
    const float* __restrict__ in, u16* __restrict__ out,
    int K, int N, size_t in_lstride, size_t out_lstride)
{
    in  += (size_t)blockIdx.z * in_lstride;
    out += (size_t)blockIdx.z * out_lstride;
    __shared__ float t[32][33];
    int bk = blockIdx.x * 32, bn = blockIdx.y * 32;
    int x = threadIdx.x & 31, y = threadIdx.x >> 5;
    #pragma unroll
    for (int i = 0; i < 32; i += 8)
        t[y + i][x] = in[(size_t)(bk + y + i) * N + bn + x];
    __syncthreads();
    #pragma unroll
    for (int i = 0; i < 32; i += 8) {
        int row = bn + y + i;
        if (PERM) row = ((row & 63) << 3) | ((row >> 6) & 7);
        out[(size_t)row * K + bk + x] = f2b(t[x][y + i]);
    }
}

// ------------------------------------------------- encode (bf16 out)
__global__ __launch_bounds__(128) void encode_kernel(
    const float* __restrict__ x, const int* __restrict__ pad,
    const float* __restrict__ W, const float* __restrict__ b,
    u16* __restrict__ h)
{
    int row = blockIdx.x;
    int t   = row & (TSEQ - 1);
    int c   = threadIdx.x * 4;
    float acc[4];
    #pragma unroll
    for (int j = 0; j < 4; ++j) acc[j] = b[c + j];
    const float* xr = x + (size_t)row * DIN;
    #pragma unroll
    for (int k = 0; k < DIN; ++k) {
        float xv = xr[k];
        const float* wr = W + (size_t)k * DM + c;
        #pragma unroll
        for (int j = 0; j < 4; ++j) acc[j] += xv * wr[j];
    }
    const float s = 22.62741699796952f;
    bool has_pe = (pad[row] != 0);
    u16x4 o;
    #pragma unroll
    for (int j = 0; j < 4; ++j) {
        acc[j] *= s;
        if (has_pe) {
            int d = c + j;
            float base = (float)t * powf(10000.0f, -(float)d * (1.0f/512.0f));
            acc[j] += ((d & 1) == 0) ? sinf(base) : cosf(base);
        }
        o[j] = f2b(acc[j]);
    }
    *(u16x4*)&h[(size_t)row * DM + c] = o;
}

// ------------------------------------------------- 128x128 MFMA GEMM, 512 threads
// BK=64, G4 swizzle, A+B double-buffered (64KB); 8 waves (2M x 4N), per-wave
// 64x32 output (acc 4x2). 2 blocks/CU x 8 waves = 16 waves/CU. (r11, session best)
template<int BIAS, int RELU>
__global__ __launch_bounds__(512, 4) void gemm_bf16(
    const u16* __restrict__ A, const u16* __restrict__ Bt,
    const float* __restrict__ bias, u16* __restrict__ C,
    int M, int N, int K)
{
    __shared__ u16 S[4][8192];   // SA0 | SB0 | SA1 | SB1 = 64 KB
    const int tid  = threadIdx.x;
    const int lane = tid & 63;
    const int wid  = tid >> 6;          // 0..7
    const int wr   = wid >> 2;          // 0..1  (M half)
    const int wc   = wid & 3;           // 0..3  (N quarter)

    // 1-D grid + bijective XCD swizzle, N-tile-fastest order
    const int NY  = N >> 7;
    const int nwg = gridDim.x;
    const int cpx = nwg >> 3;
    const int bid = blockIdx.x;
    const int swz = (bid & 7) * cpx + (bid >> 3);
    const int bm  = (swz / NY) * 128;
    const int bn  = (swz % NY) * 128;

    // staging: wave w stages rows w*16..w*16+15 (2 GLLs of 8 rows each)
    const int srow8 = lane >> 3;        // 0..7
    const int sslot = lane & 7;
    const int scol  = ((sslot ^ srow8) * 8);
    const u16* Ag = A  + (size_t)(bm + wid * 16 + srow8) * K + scol;
    const u16* Bg = Bt + (size_t)(bn + wid * 16 + srow8) * K + scol;

    f32x4 acc[4][2];
    #pragma unroll
    for (int m = 0; m < 4; ++m)
        #pragma unroll
        for (int n = 0; n < 2; ++n)
            acc[m][n] = (f32x4){0.f, 0.f, 0.f, 0.f};

    const int fr  = lane & 15;
    const int grp = lane >> 4;

    auto STAGE = [&](int k0, int d) {
        u16* Al = S[d * 2 + 0] + wid * 1024;
        u16* Bl = S[d * 2 + 1] + wid * 1024;
        #pragma unroll
        for (int i = 0; i < 2; ++i) {
            GLL(Ag + (size_t)(i * 8) * K + k0, Al + i * 512);
            GLL(Bg + (size_t)(i * 8) * K + k0, Bl + i * 512);
        }
    };

    STAGE(0, 0);
    __syncthreads();

    int cur = 0;
    for (int k0 = 0; k0 < K; k0 += 64) {
        if (k0 + 64 < K) STAGE(k0 + 64, cur ^ 1);
        const u16* As = S[cur * 2 + 0];
        const u16* Bs = S[cur * 2 + 1];
        bf16x8 a[4][2];
        #pragma unroll
        for (int m = 0; m < 4; ++m) {
            int row = wr * 64 + m * 16 + fr;
            #pragma unroll
            for (int ks = 0; ks < 2; ++ks) {
                int slot = (ks * 4 + grp) ^ (row & 7);
                a[m][ks] = *(const bf16x8*)(As + row * 64 + slot * 8);
            }
        }
        #pragma unroll
        for (int n = 0; n < 2; ++n) {
            bf16x8 b[2];
            int row = wc * 32 + n * 16 + fr;
            #pragma unroll
            for (int ks = 0; ks < 2; ++ks) {
                int slot = (ks * 4 + grp) ^ (row & 7);
                b[ks] = *(const bf16x8*)(Bs + row * 64 + slot * 8);
            }
            #pragma unroll
            for (int m = 0; m < 4; ++m) {
                acc[m][n] = __builtin_amdgcn_mfma_f32_16x16x32_bf16(a[m][0], b[0], acc[m][n], 0, 0, 0);
                acc[m][n] = __builtin_amdgcn_mfma_f32_16x16x32_bf16(a[m][1], b[1], acc[m][n], 0, 0, 0);
            }
        }
        __syncthreads();
        cur ^= 1;
    }

    float bb[2] = {0.f, 0.f};
    if (BIAS) {
        #pragma unroll
        for (int n = 0; n < 2; ++n) bb[n] = bias[bn + wc * 32 + n * 16 + fr];
    }
    #pragma unroll
    for (int m = 0; m < 4; ++m) {
        #pragma unroll
        for (int n = 0; n < 2; ++n) {
            int col = bn + wc * 32 + n * 16 + fr;
            #pragma unroll
            for (int j = 0; j < 4; ++j) {
                int row = bm + wr * 64 + m * 16 + grp * 4 + j;
                float v = acc[m][n][j];
                if (BIAS) v += bb[n];
                if (RELU) v = fmaxf(v, 0.f);
                C[(size_t)row * N + col] = f2b(v);
            }
        }
    }
}

// ------------------------------------------------- attention v3 (swapped QK^T)
__global__ __launch_bounds__(256) void attn_mfma(
    const u16* __restrict__ QKV, const int* __restrict__ pad,
    u16* __restrict__ O)
{
    constexpr int WLDS = 2560;   // 2048 P-half + 512 Ol
    __shared__ u16 sh[4 * WLDS];
    const int wid  = threadIdx.x >> 6;
    const int lane = threadIdx.x & 63;
    const int site = blockIdx.x * 4 + wid;
    u16* P2 = sh + wid * WLDS;
    u16* Ol = P2 + 2048;

    const u16* base = QKV + (size_t)site * 1536;
    const int fr  = lane & 15;
    const int grp = lane >> 4;
    const bf16x8 zb = {0,0,0,0,0,0,0,0};
    const f32x4  zf = {0.f,0.f,0.f,0.f};

    if (pad[site] == 0) {
        bf16x8 vv = *(const bf16x8*)(base + 1024 + lane * 8);
        float s = 0.f;
        #pragma unroll
        for (int j = 0; j < 8; ++j) s += b2f((u16)vv[j]);
        s += __shfl_xor(s, 1); s += __shfl_xor(s, 2); s += __shfl_xor(s, 4);
        s *= (1.0f / 64.0f);
        bf16x8 ov;
        #pragma unroll
        for (int h2 = 0; h2 < 8; ++h2) ov[h2] = (short)f2b(__shfl(s, h2 * 8));
        *(bf16x8*)(O + (size_t)site * DM + lane * 8) = ov;
        return;
    }

    bf16x8 kt[4];
    #pragma unroll
    for (int n = 0; n < 4; ++n)
        kt[n] = (grp == 0) ? *(const bf16x8*)(base + 512 + (n * 16 + fr) * 8) : zb;
    bf16x8 bv[2];
    #pragma unroll
    for (int ks = 0; ks < 2; ++ks)
        bv[ks] = (fr < 8) ? *(const bf16x8*)(base + 1024 + fr * 64 + ks * 32 + grp * 8) : zb;

    const int swz = (fr & 3) ^ (fr >> 2);
    u16x4 pk23[4][2];

    #pragma unroll
    for (int m = 0; m < 4; ++m) {
        bf16x8 aq = (grp == 0) ? *(const bf16x8*)(base + (m * 16 + fr) * 8) : zb;
        f32x4 ev[4];
        #pragma unroll
        for (int n = 0; n < 4; ++n)
            ev[n] = __builtin_amdgcn_mfma_f32_16x16x32_bf16(kt[n], aq, zf, 0, 0, 0);
        f32x4 t0, t1;
        #pragma unroll
        for (int j = 0; j < 4; ++j) { t0[j] = fmaxf(ev[0][j], ev[1][j]); t1[j] = fmaxf(ev[2][j], ev[3][j]); }
        float mx = -1e30f;
        #pragma unroll
        for (int j = 0; j < 4; ++j) mx = fmaxf(mx, fmaxf(t0[j], t1[j]));
        mx = fmaxf(mx, __shfl_xor(mx, 16));
        mx = fmaxf(mx, __shfl_xor(mx, 32));
        float p[4][4];
        float s = 0.f;
        #pragma unroll
        for (int n = 0; n < 4; ++n)
            #pragma unroll
            for (int j = 0; j < 4; ++j) {
                p[n][j] = __expf((ev[n][j] - mx) * 0.03125f);
                s += p[n][j];
            }
        s += __shfl_xor(s, 16);
        s += __shfl_xor(s, 32);
        float inv = 1.0f / s;
        u16x4 pk[4];
        #pragma unroll
        for (int n = 0; n < 4; ++n)
            #pragma unroll
            for (int j = 0; j < 4; ++j) pk[n][j] = f2b(p[n][j] * inv);
        int row = m * 16 + fr;
        #pragma unroll
        for (int n = 0; n < 2; ++n) {
            int chunk = (n * 2 + (grp >> 1)) ^ swz;
            *(u16x4*)(P2 + row * 32 + chunk * 8 + (grp & 1) * 4) = pk[n];
        }
        pk23[m][0] = pk[2];
        pk23[m][1] = pk[3];
    }

    f32x4 pv[4];
    #pragma unroll
    for (int m = 0; m < 4; ++m) {
        int row = m * 16 + fr;
        bf16x8 ap = *(const bf16x8*)(P2 + row * 32 + ((grp ^ swz) * 8));
        pv[m] = __builtin_amdgcn_mfma_f32_16x16x32_bf16(ap, bv[0], zf, 0, 0, 0);
    }
    asm volatile("s_waitcnt lgkmcnt(0)" ::: "memory");
    __builtin_amdgcn_sched_barrier(0);

    #pragma unroll
    for (int m = 0; m < 4; ++m) {
        int row = m * 16 + fr;
        #pragma unroll
        for (int n = 0; n < 2; ++n) {
            int chunk = (n * 2 + (grp >> 1)) ^ swz;
            *(u16x4*)(P2 + row * 32 + chunk * 8 + (grp & 1) * 4) = pk23[m][n];
        }
    }
    #pragma unroll
    for (int m = 0; m < 4; ++m) {
        int row = m * 16 + fr;
        bf16x8 ap = *(const bf16x8*)(P2 + row * 32 + ((grp ^ swz) * 8));
        pv[m] = __builtin_amdgcn_mfma_f32_16x16x32_bf16(ap, bv[1], pv[m], 0, 0, 0);
    }

    #pragma unroll
    for (int m = 0; m < 4; ++m)
        #pragma unroll
        for (int j = 0; j < 4; ++j) {
            int row = m * 16 + grp * 4 + j;
            if (fr < 8) Ol[row * 8 + fr] = f2b(pv[m][j]);
        }
    __syncthreads();
    bf16x8 o = *(const bf16x8*)(Ol + lane * 8);
    *(bf16x8*)(O + (size_t)site * DM + lane * 8) = o;
}

// ------------------------------------------------- residual add + layernorm (bf16)
__global__ __launch_bounds__(256) void add_ln_kernel(
    const u16* __restrict__ A, u16* __restrict__ H,
    const float* __restrict__ g, const float* __restrict__ b)
{
    int row  = blockIdx.x * 4 + (threadIdx.x >> 6);
    int lane = threadIdx.x & 63;
    const u16* a = A + (size_t)row * DM + lane * 8;
    u16* h = H + (size_t)row * DM + lane * 8;
    bf16x8 av = *(const bf16x8*)a;
    bf16x8 hv = *(const bf16x8*)h;
    float v[8];
    float s = 0.f;
    #pragma unroll
    for (int j = 0; j < 8; ++j) { v[j] = b2f((u16)av[j]) + b2f((u16)hv[j]); s += v[j]; }
    #pragma unroll
    for (int off = 32; off > 0; off >>= 1) s += __shfl_xor(s, off, 64);
    float mean = s * (1.0f / 512.0f);
    float var = 0.f;
    #pragma unroll
    for (int j = 0; j < 8; ++j) { float d = v[j] - mean; var += d * d; }
    #pragma unroll
    for (int off = 32; off > 0; off >>= 1) var += __shfl_xor(var, off, 64);
    float rstd = rsqrtf(var * (1.0f / 512.0f) + 1e-5f);
    bf16x8 ov;
    #pragma unroll
    for (int j = 0; j < 8; ++j) {
        int d = lane * 8 + j;
        ov[j] = (short)f2b((v[j] - mean) * rstd * g[d] + b[d]);
    }
    *(bf16x8*)h = ov;
}

// ------------------------------------------------- final projection
__global__ __launch_bounds__(256) void out_stage1(
    const u16* __restrict__ h, const float* __restrict__ W,
    float* __restrict__ partial)
{
    int b = blockIdx.x, s = blockIdx.y;
    int tid = threadIdx.x;
    const u16* hb = h + (size_t)b * (TSEQ * DM) + (size_t)s * 8192;
    const float* Wb = W + (size_t)s * 8192 * 3;
    float a0 = 0.f, a1 = 0.f, a2 = 0.f;
    #pragma unroll 4
    for (int it = 0; it < 32; ++it) {
        int i = it * 256 + tid;
        float hv = b2f(hb[i]);
        a0 += hv * Wb[i * 3 + 0];
        a1 += hv * Wb[i * 3 + 1];
        a2 += hv * Wb[i * 3 + 2];
    }
    __shared__ float red[3][256];
    red[0][tid] = a0; red[1][tid] = a1; red[2][tid] = a2;
    __syncthreads();
    for (int off = 128; off > 0; off >>= 1) {
        if (tid < off) {
            red[0][tid] += red[0][tid + off];
            red[1][tid] += red[1][tid + off];
            red[2][tid] += red[2][tid + off];
        }
        __syncthreads();
    }
    if (tid == 0) {
        partial[(b * 64 + s) * 3 + 0] = red[0][0];
        partial[(b * 64 + s) * 3 + 1] = red[1][0];
        partial[(b * 64 + s) * 3 + 2] = red[2][0];
    }
}

__global__ __launch_bounds__(64) void out_stage2(
    const float* __restrict__ partial, const float* __restrict__ ob,
    float* __restrict__ out)
{
    int t = threadIdx.x;
    if (t < NB * DOUTN) {
        int b = t / 3, o = t % 3;
        float s = ob[o];
        for (int k = 0; k < 64; ++k) s += partial[(b * 64 + k) * 3 + o];
        out[t] = s;
    }
}

// ------------------------------------------------- launch
extern "C" void kernel_launch(void* const* d_in, const int* in_sizes, int n_in,
                              void* d_out, int out_size, void* d_ws, size_t ws_size,
                              hipStream_t stream)
{
    const float* x    = (const float*)d_in[0];
    const int*   pad  = (const int*)  d_in[1];
    const float* encW = (const float*)d_in[2];
    const float* encB = (const float*)d_in[3];
    const float* Wq   = (const float*)d_in[4];
    const float* Wk   = (const float*)d_in[5];
    const float* Wv   = (const float*)d_in[6];
    const float* Wo   = (const float*)d_in[7];
    const float* fW1  = (const float*)d_in[8];
    const float* fb1  = (const float*)d_in[9];
    const float* fW2  = (const float*)d_in[10];
    const float* fb2  = (const float*)d_in[11];
    const float* l1g  = (const float*)d_in[12];
    const float* l1b  = (const float*)d_in[13];
    const float* l2g  = (const float*)d_in[14];
    const float* l2b  = (const float*)d_in[15];
    const float* outW = (const float*)d_in[16];
    const float* outB = (const float*)d_in[17];
    float* out = (float*)d_out;

    const size_t WL  = 3145728;
    const size_t BUF = (size_t)ROWS * DM;
    const size_t need = (4 * WL + 6 * BUF) * sizeof(u16);
    if (ws_size < need) return;
    u16* wt = (u16*)d_ws;
    u16* h  = wt + 4 * WL;
    u16* b0 = h  + BUF;
    u16* b3 = b0 + 3 * BUF;
    u16* b4 = b3 + BUF;

    transpose_cast<1><<<dim3(16,16,4), 256, 0, stream>>>(Wq,  wt + 0,       512,  512,  (size_t)512*512,  WL);
    transpose_cast<1><<<dim3(16,16,4), 256, 0, stream>>>(Wk,  wt + 262144,  512,  512,  (size_t)512*512,  WL);
    transpose_cast<0><<<dim3(16,16,4), 256, 0, stream>>>(Wv,  wt + 524288,  512,  512,  (size_t)512*512,  WL);
    transpose_cast<0><<<dim3(16,16,4), 256, 0, stream>>>(Wo,  wt + 786432,  512,  512,  (size_t)512*512,  WL);
    transpose_cast<0><<<dim3(16,64,4), 256, 0, stream>>>(fW1, wt + 1048576, 512,  2048, (size_t)512*2048, WL);
    transpose_cast<0><<<dim3(64,16,4), 256, 0, stream>>>(fW2, wt + 2097152, 2048, 512,  (size_t)2048*512, WL);

    encode_kernel<<<ROWS, 128, 0, stream>>>(x, pad, encW, encB, h);

    for (int l = 0; l < NLAYERS; ++l) {
        u16* wl = wt + (size_t)l * WL;
        gemm_bf16<0,0><<<dim3((ROWS/128)*(1536/128)), 512, 0, stream>>>(h, wl, nullptr, b0, ROWS, 1536, DM);
        attn_mfma<<<ROWS/4, 256, 0, stream>>>(b0, pad, b3);
        gemm_bf16<0,0><<<dim3((ROWS/128)*(DM/128)), 512, 0, stream>>>(b3, wl + 786432, nullptr, b4, ROWS, DM, DM);
        add_ln_kernel<<<ROWS/4, 256, 0, stream>>>(b4, h, l1g + l*DM, l1b + l*DM);
        gemm_bf16<1,1><<<dim3((ROWS/128)*(DFFN/128)), 512, 0, stream>>>(h, wl + 1048576, fb1 + (size_t)l*DFFN, b0, ROWS, DFFN, DM);
        gemm_bf16<1,0><<<dim3((ROWS/128)*(DM/128)), 512, 0, stream>>>(b0, wl + 2097152, fb2 + (size_t)l*DM, b4, ROWS, DM, DFFN);
        add_ln_kernel<<<ROWS/4, 256, 0, stream>>>(b4, h, l2g + l*DM, l2b + l*DM);
    }

    out_stage1<<<dim3(NB, 64), 256, 0, stream>>>(h, outW, (float*)b0);
    out_stage2<<<1, 64, 0, stream>>>((float*)b0, outB, out);
}

// Round 18
// 726.744 us; speedup vs baseline: 1.2603x; 1.0166x over previous
//
#include <hip/hip_runtime.h>
#include <cmath>

#define NB 16
#define TSEQ 1024
#define DIN 16
#define DM 512
#define DFFN 2048
#define NLAYERS 4
#define DOUTN 3
#define ROWS (NB*TSEQ)   /* 16384 */

typedef unsigned short u16;
typedef unsigned int   u32;
typedef short bf16x8 __attribute__((ext_vector_type(8)));
typedef u16   u16x4  __attribute__((ext_vector_type(4)));
typedef float f32x4  __attribute__((ext_vector_type(4)));

__device__ __forceinline__ float b2f(u16 v) { return __uint_as_float((unsigned)v << 16); }
__device__ __forceinline__ u16 f2b(float f) {
    unsigned u = __float_as_uint(f);
    return (u16)((u + 0x7FFFu + ((u >> 16) & 1u)) >> 16);
}

#define GLL(gp, lp) __builtin_amdgcn_global_load_lds( \
    (const __attribute__((address_space(1))) unsigned int*)(gp), \
    (__attribute__((address_space(3))) unsigned int*)(lp), 16, 0, 0)

// ------------------------------------------------- weight transpose + cast
template<int PERM>
__global__ __launch_bounds__(256) void transpose_cast(
    const float* __restrict__ in, u16* __restrict__ out,
    int K, int N, size_t in_lstride, size_t out_lstride)
{
    in  += (size_t)blockIdx.z * in_lstride;
    out += (size_t)blockIdx.z * out_lstride;
    __shared__ float t[32][33];
    int bk = blockIdx.x * 32, bn = blockIdx.y * 32;
    int x = threadIdx.x & 31, y = threadIdx.x >> 5;
    #pragma unroll
    for (int i = 0; i < 32; i += 8)
        t[y + i][x] = in[(size_t)(bk + y + i) * N + bn + x];
    __syncthreads();
    #pragma unroll
    for (int i = 0; i < 32; i += 8) {
        int row = bn + y + i;
        if (PERM) row = ((row & 63) << 3) | ((row >> 6) & 7);
        out[(size_t)row * K + bk + x] = f2b(t[x][y + i]);
    }
}

// ------------------------------------------------- PE table (once per launch)
// pe[t][d] = sin/cos(t * 10000^(-d/512)); 1024x512 f32 (2 MB).
__global__ __launch_bounds__(128) void pe_table_kernel(float* __restrict__ pe)
{
    int t = blockIdx.x;
    int c = threadIdx.x * 4;
    f32x4 o;
    #pragma unroll
    for (int j = 0; j < 4; ++j) {
        int d = c + j;
        float base = (float)t * powf(10000.0f, -(float)d * (1.0f/512.0f));
        o[j] = ((d & 1) == 0) ? sinf(base) : cosf(base);
    }
    *(f32x4*)&pe[(size_t)t * DM + c] = o;
}

// ------------------------------------------------- encode (bf16 out, table PE)
__global__ __launch_bounds__(128) void encode_kernel(
    const float* __restrict__ x, const int* __restrict__ pad,
    const float* __restrict__ W, const float* __restrict__ b,
    const float* __restrict__ pe, u16* __restrict__ h)
{
    int row = blockIdx.x;
    int t   = row & (TSEQ - 1);
    int c   = threadIdx.x * 4;
    float acc[4];
    #pragma unroll
    for (int j = 0; j < 4; ++j) acc[j] = b[c + j];
    const float* xr = x + (size_t)row * DIN;
    #pragma unroll
    for (int k = 0; k < DIN; ++k) {
        float xv = xr[k];
        const float* wr = W + (size_t)k * DM + c;
        #pragma unroll
        for (int j = 0; j < 4; ++j) acc[j] += xv * wr[j];
    }
    const float s = 22.62741699796952f;
    bool has_pe = (pad[row] != 0);
    f32x4 pv = *(const f32x4*)&pe[(size_t)t * DM + c];
    u16x4 o;
    #pragma unroll
    for (int j = 0; j < 4; ++j) {
        acc[j] *= s;
        if (has_pe) acc[j] += pv[j];
        o[j] = f2b(acc[j]);
    }
    *(u16x4*)&h[(size_t)row * DM + c] = o;
}

// ------------------------------------------------- 128x128 MFMA GEMM, 512 threads
// BK=64, G4 swizzle, A+B double-buffered (64KB); 8 waves (2M x 4N), per-wave
// 64x32 output (acc 4x2). Epilogue: C staged in freed LDS -> coalesced 16B stores.
template<int BIAS, int RELU>
__global__ __launch_bounds__(512, 4) void gemm_bf16(
    const u16* __restrict__ A, const u16* __restrict__ Bt,
    const float* __restrict__ bias, u16* __restrict__ C,
    int M, int N, int K)
{
    __shared__ u16 S[4][8192];   // SA0 | SB0 | SA1 | SB1 = 64 KB
    const int tid  = threadIdx.x;
    const int lane = tid & 63;
    const int wid  = tid >> 6;          // 0..7
    const int wr   = wid >> 2;          // 0..1  (M half)
    const int wc   = wid & 3;           // 0..3  (N quarter)

    // 1-D grid + bijective XCD swizzle, N-tile-fastest order
    const int NY  = N >> 7;
    const int nwg = gridDim.x;
    const int cpx = nwg >> 3;
    const int bid = blockIdx.x;
    const int swz = (bid & 7) * cpx + (bid >> 3);
    const int bm  = (swz / NY) * 128;
    const int bn  = (swz % NY) * 128;

    const int srow8 = lane >> 3;
    const int sslot = lane & 7;
    const int scol  = ((sslot ^ srow8) * 8);
    const u16* Ag = A  + (size_t)(bm + wid * 16 + srow8) * K + scol;
    const u16* Bg = Bt + (size_t)(bn + wid * 16 + srow8) * K + scol;

    f32x4 acc[4][2];
    #pragma unroll
    for (int m = 0; m < 4; ++m)
        #pragma unroll
        for (int n = 0; n < 2; ++n)
            acc[m][n] = (f32x4){0.f, 0.f, 0.f, 0.f};

    const int fr  = lane & 15;
    const int grp = lane >> 4;

    auto STAGE = [&](int k0, int d) {
        u16* Al = S[d * 2 + 0] + wid * 1024;
        u16* Bl = S[d * 2 + 1] + wid * 1024;
        #pragma unroll
        for (int i = 0; i < 2; ++i) {
            GLL(Ag + (size_t)(i * 8) * K + k0, Al + i * 512);
            GLL(Bg + (size_t)(i * 8) * K + k0, Bl + i * 512);
        }
    };

    STAGE(0, 0);
    __syncthreads();

    int cur = 0;
    for (int k0 = 0; k0 < K; k0 += 64) {
        if (k0 + 64 < K) STAGE(k0 + 64, cur ^ 1);
        const u16* As = S[cur * 2 + 0];
        const u16* Bs = S[cur * 2 + 1];
        bf16x8 a[4][2];
        #pragma unroll
        for (int m = 0; m < 4; ++m) {
            int row = wr * 64 + m * 16 + fr;
            #pragma unroll
            for (int ks = 0; ks < 2; ++ks) {
                int slot = (ks * 4 + grp) ^ (row & 7);
                a[m][ks] = *(const bf16x8*)(As + row * 64 + slot * 8);
            }
        }
        #pragma unroll
        for (int n = 0; n < 2; ++n) {
            bf16x8 b[2];
            int row = wc * 32 + n * 16 + fr;
            #pragma unroll
            for (int ks = 0; ks < 2; ++ks) {
                int slot = (ks * 4 + grp) ^ (row & 7);
                b[ks] = *(const bf16x8*)(Bs + row * 64 + slot * 8);
            }
            #pragma unroll
            for (int m = 0; m < 4; ++m) {
                acc[m][n] = __builtin_amdgcn_mfma_f32_16x16x32_bf16(a[m][0], b[0], acc[m][n], 0, 0, 0);
                acc[m][n] = __builtin_amdgcn_mfma_f32_16x16x32_bf16(a[m][1], b[1], acc[m][n], 0, 0, 0);
            }
        }
        __syncthreads();
        cur ^= 1;
    }

    // ---- epilogue: stage tile in freed LDS [128][136] (272B row stride, 16B-aligned),
    //      then 4 fully-coalesced 16B stores per thread.
    float bb[2] = {0.f, 0.f};
    if (BIAS) {
        #pragma unroll
        for (int n = 0; n < 2; ++n) bb[n] = bias[bn + wc * 32 + n * 16 + fr];
    }
    u16* Cs = (u16*)S;
    #pragma unroll
    for (int m = 0; m < 4; ++m)
        #pragma unroll
        for (int n = 0; n < 2; ++n)
            #pragma unroll
            for (int j = 0; j < 4; ++j) {
                int r = wr * 64 + m * 16 + grp * 4 + j;
                int c = wc * 32 + n * 16 + fr;
                float v = acc[m][n][j];
                if (BIAS) v += bb[n];
                if (RELU) v = fmaxf(v, 0.f);
                Cs[r * 136 + c] = f2b(v);
            }
    __syncthreads();
    #pragma unroll
    for (int p = 0; p < 4; ++p) {
        int r = p * 32 + (tid >> 4);
        int c = (tid & 15) * 8;
        bf16x8 v = *(const bf16x8*)(Cs + r * 136 + c);
        *(bf16x8*)(C + (size_t)(bm + r) * N + bn + c) = v;
    }
}

// ------------------------------------------------- attention v3 (swapped QK^T)
__global__ __launch_bounds__(256) void attn_mfma(
    const u16* __restrict__ QKV, const int* __restrict__ pad,
    u16* __restrict__ O)
{
    constexpr int WLDS = 2560;   // 2048 P-half + 512 Ol
    __shared__ u16 sh[4 * WLDS];
    const int wid  = threadIdx.x >> 6;
    const int lane = threadIdx.x & 63;
    const int site = blockIdx.x * 4 + wid;
    u16* P2 = sh + wid * WLDS;
    u16* Ol = P2 + 2048;

    const u16* base = QKV + (size_t)site * 1536;
    const int fr  = lane & 15;
    const int grp = lane >> 4;
    const bf16x8 zb = {0,0,0,0,0,0,0,0};
    const f32x4  zf = {0.f,0.f,0.f,0.f};

    if (pad[site] == 0) {
        bf16x8 vv = *(const bf16x8*)(base + 1024 + lane * 8);
        float s = 0.f;
        #pragma unroll
        for (int j = 0; j < 8; ++j) s += b2f((u16)vv[j]);
        s += __shfl_xor(s, 1); s += __shfl_xor(s, 2); s += __shfl_xor(s, 4);
        s *= (1.0f / 64.0f);
        bf16x8 ov;
        #pragma unroll
        for (int h2 = 0; h2 < 8; ++h2) ov[h2] = (short)f2b(__shfl(s, h2 * 8));
        *(bf16x8*)(O + (size_t)site * DM + lane * 8) = ov;
        return;
    }

    bf16x8 kt[4];
    #pragma unroll
    for (int n = 0; n < 4; ++n)
        kt[n] = (grp == 0) ? *(const bf16x8*)(base + 512 + (n * 16 + fr) * 8) : zb;
    bf16x8 bv[2];
    #pragma unroll
    for (int ks = 0; ks < 2; ++ks)
        bv[ks] = (fr < 8) ? *(const bf16x8*)(base + 1024 + fr * 64 + ks * 32 + grp * 8) : zb;

    const int swz = (fr & 3) ^ (fr >> 2);
    u16x4 pk23[4][2];

    #pragma unroll
    for (int m = 0; m < 4; ++m) {
        bf16x8 aq = (grp == 0) ? *(const bf16x8*)(base + (m * 16 + fr) * 8) : zb;
        f32x4 ev[4];
        #pragma unroll
        for (int n = 0; n < 4; ++n)
            ev[n] = __builtin_amdgcn_mfma_f32_16x16x32_bf16(kt[n], aq, zf, 0, 0, 0);
        f32x4 t0, t1;
        #pragma unroll
        for (int j = 0; j < 4; ++j) { t0[j] = fmaxf(ev[0][j], ev[1][j]); t1[j] = fmaxf(ev[2][j], ev[3][j]); }
        float mx = -1e30f;
        #pragma unroll
        for (int j = 0; j < 4; ++j) mx = fmaxf(mx, fmaxf(t0[j], t1[j]));
        mx = fmaxf(mx, __shfl_xor(mx, 16));
        mx = fmaxf(mx, __shfl_xor(mx, 32));
        float p[4][4];
        float s = 0.f;
        #pragma unroll
        for (int n = 0; n < 4; ++n)
            #pragma unroll
            for (int j = 0; j < 4; ++j) {
                p[n][j] = __expf((ev[n][j] - mx) * 0.03125f);
                s += p[n][j];
            }
        s += __shfl_xor(s, 16);
        s += __shfl_xor(s, 32);
        float inv = 1.0f / s;
        u16x4 pk[4];
        #pragma unroll
        for (int n = 0; n < 4; ++n)
            #pragma unroll
            for (int j = 0; j < 4; ++j) pk[n][j] = f2b(p[n][j] * inv);
        int row = m * 16 + fr;
        #pragma unroll
        for (int n = 0; n < 2; ++n) {
            int chunk = (n * 2 + (grp >> 1)) ^ swz;
            *(u16x4*)(P2 + row * 32 + chunk * 8 + (grp & 1) * 4) = pk[n];
        }
        pk23[m][0] = pk[2];
        pk23[m][1] = pk[3];
    }

    f32x4 pv[4];
    #pragma unroll
    for (int m = 0; m < 4; ++m) {
        int row = m * 16 + fr;
        bf16x8 ap = *(const bf16x8*)(P2 + row * 32 + ((grp ^ swz) * 8));
        pv[m] = __builtin_amdgcn_mfma_f32_16x16x32_bf16(ap, bv[0], zf, 0, 0, 0);
    }
    asm volatile("s_waitcnt lgkmcnt(0)" ::: "memory");
    __builtin_amdgcn_sched_barrier(0);

    #pragma unroll
    for (int m = 0; m < 4; ++m) {
        int row = m * 16 + fr;
        #pragma unroll
        for (int n = 0; n < 2; ++n) {
            int chunk = (n * 2 + (grp >> 1)) ^ swz;
            *(u16x4*)(P2 + row * 32 + chunk * 8 + (grp & 1) * 4) = pk23[m][n];
        }
    }
    #pragma unroll
    for (int m = 0; m < 4; ++m) {
        int row = m * 16 + fr;
        bf16x8 ap = *(const bf16x8*)(P2 + row * 32 + ((grp ^ swz) * 8));
        pv[m] = __builtin_amdgcn_mfma_f32_16x16x32_bf16(ap, bv[1], pv[m], 0, 0, 0);
    }

    // epilogue stage: per-wave LDS region, same-wave lockstep -> no barrier needed
    #pragma unroll
    for (int m = 0; m < 4; ++m)
        #pragma unroll
        for (int j = 0; j < 4; ++j) {
            int row = m * 16 + grp * 4 + j;
            if (fr < 8) Ol[row * 8 + fr] = f2b(pv[m][j]);
        }
    bf16x8 o = *(const bf16x8*)(Ol + lane * 8);
    *(bf16x8*)(O + (size_t)site * DM + lane * 8) = o;
}

// ------------------------------------------------- residual add + layernorm (bf16)
__global__ __launch_bounds__(256) void add_ln_kernel(
    const u16* __restrict__ A, u16* __restrict__ H,
    const float* __restrict__ g, const float* __restrict__ b)
{
    int row  = blockIdx.x * 4 + (threadIdx.x >> 6);
    int lane = threadIdx.x & 63;
    const u16* a = A + (size_t)row * DM + lane * 8;
    u16* h = H + (size_t)row * DM + lane * 8;
    bf16x8 av = *(const bf16x8*)a;
    bf16x8 hv = *(const bf16x8*)h;
    float v[8];
    float s = 0.f;
    #pragma unroll
    for (int j = 0; j < 8; ++j) { v[j] = b2f((u16)av[j]) + b2f((u16)hv[j]); s += v[j]; }
    #pragma unroll
    for (int off = 32; off > 0; off >>= 1) s += __shfl_xor(s, off, 64);
    float mean = s * (1.0f / 512.0f);
    float var = 0.f;
    #pragma unroll
    for (int j = 0; j < 8; ++j) { float d = v[j] - mean; var += d * d; }
    #pragma unroll
    for (int off = 32; off > 0; off >>= 1) var += __shfl_xor(var, off, 64);
    float rstd = rsqrtf(var * (1.0f / 512.0f) + 1e-5f);
    bf16x8 ov;
    #pragma unroll
    for (int j = 0; j < 8; ++j) {
        int d = lane * 8 + j;
        ov[j] = (short)f2b((v[j] - mean) * rstd * g[d] + b[d]);
    }
    *(bf16x8*)h = ov;
}

// ------------------------------------------------- final projection
__global__ __launch_bounds__(256) void out_stage1(
    const u16* __restrict__ h, const float* __restrict__ W,
    float* __restrict__ partial)
{
    int b = blockIdx.x, s = blockIdx.y;
    int tid = threadIdx.x;
    const u16* hb = h + (size_t)b * (TSEQ * DM) + (size_t)s * 8192;
    const float* Wb = W + (size_t)s * 8192 * 3;
    float a0 = 0.f, a1 = 0.f, a2 = 0.f;
    #pragma unroll 4
    for (int it = 0; it < 32; ++it) {
        int i = it * 256 + tid;
        float hv = b2f(hb[i]);
        a0 += hv * Wb[i * 3 + 0];
        a1 += hv * Wb[i * 3 + 1];
        a2 += hv * Wb[i * 3 + 2];
    }
    __shared__ float red[3][256];
    red[0][tid] = a0; red[1][tid] = a1; red[2][tid] = a2;
    __syncthreads();
    for (int off = 128; off > 0; off >>= 1) {
        if (tid < off) {
            red[0][tid] += red[0][tid + off];
            red[1][tid] += red[1][tid + off];
            red[2][tid] += red[2][tid + off];
        }
        __syncthreads();
    }
    if (tid == 0) {
        partial[(b * 64 + s) * 3 + 0] = red[0][0];
        partial[(b * 64 + s) * 3 + 1] = red[1][0];
        partial[(b * 64 + s) * 3 + 2] = red[2][0];
    }
}

__global__ __launch_bounds__(64) void out_stage2(
    const float* __restrict__ partial, const float* __restrict__ ob,
    float* __restrict__ out)
{
    int t = threadIdx.x;
    if (t < NB * DOUTN) {
        int b = t / 3, o = t % 3;
        float s = ob[o];
        for (int k = 0; k < 64; ++k) s += partial[(b * 64 + k) * 3 + o];
        out[t] = s;
    }
}

// ------------------------------------------------- launch
extern "C" void kernel_launch(void* const* d_in, const int* in_sizes, int n_in,
                              void* d_out, int out_size, void* d_ws, size_t ws_size,
                              hipStream_t stream)
{
    const float* x    = (const float*)d_in[0];
    const int*   pad  = (const int*)  d_in[1];
    const float* encW = (const float*)d_in[2];
    const float* encB = (const float*)d_in[3];
    const float* Wq   = (const float*)d_in[4];
    const float* Wk   = (const float*)d_in[5];
    const float* Wv   = (const float*)d_in[6];
    const float* Wo   = (const float*)d_in[7];
    const float* fW1  = (const float*)d_in[8];
    const float* fb1  = (const float*)d_in[9];
    const float* fW2  = (const float*)d_in[10];
    const float* fb2  = (const float*)d_in[11];
    const float* l1g  = (const float*)d_in[12];
    const float* l1b  = (const float*)d_in[13];
    const float* l2g  = (const float*)d_in[14];
    const float* l2b  = (const float*)d_in[15];
    const float* outW = (const float*)d_in[16];
    const float* outB = (const float*)d_in[17];
    float* out = (float*)d_out;

    const size_t WL  = 3145728;
    const size_t BUF = (size_t)ROWS * DM;
    const size_t need = (4 * WL + 6 * BUF) * sizeof(u16) + (size_t)TSEQ * DM * sizeof(float);
    if (ws_size < need) return;
    u16* wt = (u16*)d_ws;
    u16* h  = wt + 4 * WL;
    u16* b0 = h  + BUF;
    u16* b3 = b0 + 3 * BUF;
    u16* b4 = b3 + BUF;
    float* pe = (float*)(b4 + BUF);   // 1024x512 f32 PE table (2 MB)

    transpose_cast<1><<<dim3(16,16,4), 256, 0, stream>>>(Wq,  wt + 0,       512,  512,  (size_t)512*512,  WL);
    transpose_cast<1><<<dim3(16,16,4), 256, 0, stream>>>(Wk,  wt + 262144,  512,  512,  (size_t)512*512,  WL);
    transpose_cast<0><<<dim3(16,16,4), 256, 0, stream>>>(Wv,  wt + 524288,  512,  512,  (size_t)512*512,  WL);
    transpose_cast<0><<<dim3(16,16,4), 256, 0, stream>>>(Wo,  wt + 786432,  512,  512,  (size_t)512*512,  WL);
    transpose_cast<0><<<dim3(16,64,4), 256, 0, stream>>>(fW1, wt + 1048576, 512,  2048, (size_t)512*2048, WL);
    transpose_cast<0><<<dim3(64,16,4), 256, 0, stream>>>(fW2, wt + 2097152, 2048, 512,  (size_t)2048*512, WL);

    pe_table_kernel<<<TSEQ, 128, 0, stream>>>(pe);
    encode_kernel<<<ROWS, 128, 0, stream>>>(x, pad, encW, encB, pe, h);

    for (int l = 0; l < NLAYERS; ++l) {
        u16* wl = wt + (size_t)l * WL;
        gemm_bf16<0,0><<<dim3((ROWS/128)*(1536/128)), 512, 0, stream>>>(h, wl, nullptr, b0, ROWS, 1536, DM);
        attn_mfma<<<ROWS/4, 256, 0, stream>>>(b0, pad, b3);
        gemm_bf16<0,0><<<dim3((ROWS/128)*(DM/128)), 512, 0, stream>>>(b3, wl + 786432, nullptr, b4, ROWS, DM, DM);
        add_ln_kernel<<<ROWS/4, 256, 0, stream>>>(b4, h, l1g + l*DM, l1b + l*DM);
        gemm_bf16<1,1><<<dim3((ROWS/128)*(DFFN/128)), 512, 0, stream>>>(h, wl + 1048576, fb1 + (size_t)l*DFFN, b0, ROWS, DFFN, DM);
        gemm_bf16<1,0><<<dim3((ROWS/128)*(DM/128)), 512, 0, stream>>>(b0, wl + 2097152, fb2 + (size_t)l*DM, b4, ROWS, DM, DFFN);
        add_ln_kernel<<<ROWS/4, 256, 0, stream>>>(b4, h, l2g + l*DM, l2b + l*DM);
    }

    out_stage1<<<dim3(NB, 64), 256, 0, stream>>>(h, outW, (float*)b0);
    out_stage2<<<1, 64, 0, stream>>>((float*)b0, outB, out);
}